// Round 9
// baseline (1690.069 us; speedup 1.0000x reference)
//
#include <hip/hip_runtime.h>
#include <hip/hip_cooperative_groups.h>
#include <float.h>

namespace cg = cooperative_groups;

#define NN 5000
#define NE 50000
#define CHW4 768       // float4 units per node row
#define MAXD 64

typedef float f32x4 __attribute__((ext_vector_type(4)));
typedef unsigned int u32x2 __attribute__((ext_vector_type(2)));

__device__ __forceinline__ unsigned int pack_bf16(float a, float b) {
  unsigned int ua = __float_as_uint(a), ub = __float_as_uint(b);
  ua = (ua + 0x7FFFu + ((ua >> 16) & 1u)) >> 16;
  ub = (ub + 0x7FFFu + ((ub >> 16) & 1u)) & 0xFFFF0000u;
  return ua | ub;
}
__device__ __forceinline__ float bf_lo(unsigned int u) { return __uint_as_float(u << 16); }
__device__ __forceinline__ float bf_hi(unsigned int u) { return __uint_as_float(u & 0xFFFF0000u); }

// ---------------- CSR build ----------------
__global__ void hist_kernel(const int* __restrict__ dst, int* __restrict__ cnt) {
  int e = blockIdx.x * 256 + threadIdx.x;
  if (e < NE) atomicAdd(&cnt[dst[e]], 1);
}

__global__ void scan_kernel(const int* __restrict__ cnt, int* __restrict__ off, int* __restrict__ cur) {
  __shared__ int tsum[256];
  int t = threadIdx.x;
  constexpr int PER = 20;
  int base = t * PER;
  int vals[PER];
  int local = 0;
#pragma unroll
  for (int i = 0; i < PER; i++) {
    int idx = base + i;
    int v = (idx < NN) ? cnt[idx] : 0;
    vals[i] = local;
    local += v;
  }
  tsum[t] = local;
  __syncthreads();
  for (int o = 1; o < 256; o <<= 1) {
    int v = (t >= o) ? tsum[t - o] : 0;
    __syncthreads();
    tsum[t] += v;
    __syncthreads();
  }
  int excl = (t == 0) ? 0 : tsum[t - 1];
#pragma unroll
  for (int i = 0; i < PER; i++) {
    int idx = base + i;
    if (idx < NN) {
      int o2 = excl + vals[i];
      off[idx] = o2;
      cur[idx] = o2;
    }
  }
  if (t == 255) off[NN] = excl + local;
}

__global__ void scatter_kernel(const int* __restrict__ dst, const int* __restrict__ src,
                               int* __restrict__ cur, int* __restrict__ eids, int* __restrict__ srcs) {
  int e = blockIdx.x * 256 + threadIdx.x;
  if (e < NE) {
    int p = atomicAdd(&cur[dst[e]], 1);
    eids[p] = e;
    srcs[p] = src[e];
  }
}

// ---------------- fused bodies ----------------
struct KArgs {
  const float* hv0;
  const float* he;
  const int* srcs;
  const int* eids;
  const int* off;
  const float* gamma;   // [3][64]
  const float* beta;    // [3][64]
  const float* Wg;      // [3][64][64]
  const float* bg;      // [3][64]
  const float* oW;      // [64][12]
  const float* ob;      // [12]
  float* hvA;
  float* hvB;
  u32x2* hvbA;
  u32x2* hvbB;
  u32x2* heb;
  float* statsN;        // [3][8][128]
  float* out;
};

__device__ __forceinline__ void do_init(const KArgs& a) {
  __shared__ float ibsum[64], ibsq[64];
  int t = threadIdx.x;
  const float4* hv4 = (const float4*)a.hv0;
  for (int n = blockIdx.x; n < NN; n += gridDim.x) {
    if (t < 64) {
      ibsum[t] = 0.f;
      ibsq[t] = 0.f;
    }
    __syncthreads();
#pragma unroll
    for (int j = 0; j < 3; j++) {
      int q = t + j * 256;
      int c = q / 12;
      float4 v = hv4[(size_t)n * CHW4 + q];
      u32x2 o;
      o.x = pack_bf16(v.x, v.y);
      o.y = pack_bf16(v.z, v.w);
      a.hvbA[(size_t)n * CHW4 + q] = o;
      atomicAdd(&ibsum[c], v.x + v.y + v.z + v.w);
      atomicAdd(&ibsq[c], v.x * v.x + v.y * v.y + v.z * v.z + v.w * v.w);
    }
    __syncthreads();
    int r = n & 7;
    if (t < 64) atomicAdd(&a.statsN[r * 128 + t], ibsum[t]);
    else if (t < 128) atomicAdd(&a.statsN[r * 128 + 64 + (t - 64)], ibsq[t - 64]);
    __syncthreads();
  }
}

__device__ __forceinline__ void do_layer(const KArgs& a, int l) {
  __shared__ float fl[3072];
  __shared__ float scl[64], shl[64];
  __shared__ int sS[MAXD], sE[MAXD];
  __shared__ float bsum[64], bsq[64];

  int t = threadIdx.x;
  const float* hvPrev = (l == 0) ? a.hv0 : (l == 1 ? a.hvA : a.hvB);
  float* hvNext = (l == 0) ? a.hvA : a.hvB;
  const u32x2* mirIn = (l & 1) ? a.hvbB : a.hvbA;
  u32x2* mirOut = (l & 1) ? a.hvbA : a.hvbB;
  float* statsNext = a.statsN + (l + 1) * 1024;
  const float* WgL = a.Wg + l * 4096;
  const float* bgL = a.bg + l * 64;
  const bool first = (l == 0), last = (l == 2);

  // per-block BN finalize (statsN complete after previous grid sync)
  if (t < 64) {
    const float* sN = a.statsN + l * 1024;
    float s = 0.f, q = 0.f;
#pragma unroll
    for (int r = 0; r < 8; r++) {
      s += sN[r * 128 + t];
      q += sN[r * 128 + 64 + t];
    }
    const float inv = 1.f / 240000.f;
    float mu = s * inv;
    float var = q * inv - mu * mu;
    float scale = a.gamma[l * 64 + t] * rsqrtf(var + 1e-5f);
    scl[t] = scale;
    shl[t] = a.beta[l * 64 + t] - mu * scale;
  }
  __syncthreads();

  const float4* hv4 = (const float4*)hvPrev;
  const f32x4* heV = (const f32x4*)a.he;
  const float4* w4 = (const float4*)WgL;
  float4* fl4 = (float4*)fl;

  for (int n = blockIdx.x; n < NN; n += gridDim.x) {
    if (!last && t < 64) {
      bsum[t] = 0.f;
      bsq[t] = 0.f;
    }

    float scv[3], shv[3], h1[12];
#pragma unroll
    for (int j = 0; j < 3; j++) {
      int q = t + j * 256;
      int c = q / 12;
      scv[j] = scl[c];
      shv[j] = shl[c];
      float4 v = hv4[(size_t)n * CHW4 + q];
      h1[4 * j + 0] = fmaxf(v.x * scv[j] + shv[j], 0.f);
      h1[4 * j + 1] = fmaxf(v.y * scv[j] + shv[j], 0.f);
      h1[4 * j + 2] = fmaxf(v.z * scv[j] + shv[j], 0.f);
      h1[4 * j + 3] = fmaxf(v.w * scv[j] + shv[j], 0.f);
    }

    float S[12], T[12];
#pragma unroll
    for (int i = 0; i < 12; i++) {
      S[i] = 0.f;
      T[i] = 0.f;
    }

    int e0 = a.off[n], d = a.off[n + 1] - e0;
    for (int base = 0; base < d; base += MAXD) {
      int cnt = min(MAXD, d - base);
      __syncthreads();
      if (t < cnt) {
        sS[t] = a.srcs[e0 + base + t];
        if (first) sE[t] = a.eids[e0 + base + t];
      }
      __syncthreads();
      if (first) {
#pragma unroll 2
        for (int k = 0; k < cnt; k++) {
          size_t hb = (size_t)sS[k] * CHW4;
          size_t pbq = (size_t)(e0 + base + k) * CHW4;
#pragma unroll
          for (int j = 0; j < 3; j++) {
            int q = t + j * 256;
            u32x2 hg = mirIn[hb + q];
            float hgf[4];
            hgf[0] = fmaxf(bf_lo(hg.x) * scv[j] + shv[j], 0.f);
            hgf[1] = fmaxf(bf_hi(hg.x) * scv[j] + shv[j], 0.f);
            hgf[2] = fmaxf(bf_lo(hg.y) * scv[j] + shv[j], 0.f);
            hgf[3] = fmaxf(bf_hi(hg.y) * scv[j] + shv[j], 0.f);
            f32x4 b = __builtin_nontemporal_load(&heV[(size_t)sE[k] * CHW4 + q]);
            u32x2 o;
            o.x = pack_bf16(b.x, b.y);
            o.y = pack_bf16(b.z, b.w);
            __builtin_nontemporal_store(o, &a.heb[pbq + q]);
            float hef[4] = {b.x, b.y, b.z, b.w};
#pragma unroll
            for (int u = 0; u < 4; u++) {
              float m = fmaxf(hgf[u] + hef[u], 0.f) + 1e-7f;
              float e = __expf(m);  // shift-free softmax: m bounded
              int idx = j * 4 + u;
              S[idx] += e;
              T[idx] += e * m;
            }
          }
        }
      } else {
#pragma unroll 2
        for (int k = 0; k < cnt; k++) {
          size_t hb = (size_t)sS[k] * CHW4;
          size_t pbq = (size_t)(e0 + base + k) * CHW4;
#pragma unroll
          for (int j = 0; j < 3; j++) {
            int q = t + j * 256;
            u32x2 hg = mirIn[hb + q];
            float hgf[4];
            hgf[0] = fmaxf(bf_lo(hg.x) * scv[j] + shv[j], 0.f);
            hgf[1] = fmaxf(bf_hi(hg.x) * scv[j] + shv[j], 0.f);
            hgf[2] = fmaxf(bf_lo(hg.y) * scv[j] + shv[j], 0.f);
            hgf[3] = fmaxf(bf_hi(hg.y) * scv[j] + shv[j], 0.f);
            u32x2 bb = __builtin_nontemporal_load(&a.heb[pbq + q]);
            float hef[4] = {bf_lo(bb.x), bf_hi(bb.x), bf_lo(bb.y), bf_hi(bb.y)};
#pragma unroll
            for (int u = 0; u < 4; u++) {
              float m = fmaxf(hgf[u] + hef[u], 0.f) + 1e-7f;
              float e = __expf(m);
              int idx = j * 4 + u;
              S[idx] += e;
              T[idx] += e * m;
            }
          }
        }
      }
    }

    bool hasE = d > 0;
#pragma unroll
    for (int j = 0; j < 3; j++) {
      int q = t + j * 256, idx = 4 * j;
      float4 f;
      f.x = h1[idx + 0] + (hasE ? T[idx + 0] / S[idx + 0] : 0.f);
      f.y = h1[idx + 1] + (hasE ? T[idx + 1] / S[idx + 1] : 0.f);
      f.z = h1[idx + 2] + (hasE ? T[idx + 2] / S[idx + 2] : 0.f);
      f.w = h1[idx + 3] + (hasE ? T[idx + 3] / S[idx + 3] : 0.f);
      fl4[q] = f;
    }
    __syncthreads();

    // linear: 192 threads, 4 out-channels x 1 h-position each; W from global (L1-resident)
    int o0 = (t / 12) * 4, hbp = t % 12;
    float4 acc[4];
    if (t < 192) {
#pragma unroll
      for (int i = 0; i < 4; i++) {
        float bv = bgL[o0 + i];
        acc[i] = make_float4(bv, bv, bv, bv);
      }
      int widx = o0 >> 2;
      for (int c2 = 0; c2 < 64; c2++) {
        float4 fv = fl4[c2 * 12 + hbp];
        float4 wv = w4[c2 * 16 + widx];
        acc[0].x += wv.x * fv.x; acc[0].y += wv.x * fv.y; acc[0].z += wv.x * fv.z; acc[0].w += wv.x * fv.w;
        acc[1].x += wv.y * fv.x; acc[1].y += wv.y * fv.y; acc[1].z += wv.y * fv.z; acc[1].w += wv.y * fv.w;
        acc[2].x += wv.z * fv.x; acc[2].y += wv.z * fv.y; acc[2].z += wv.z * fv.z; acc[2].w += wv.z * fv.w;
        acc[3].x += wv.w * fv.x; acc[3].y += wv.w * fv.y; acc[3].z += wv.w * fv.z; acc[3].w += wv.w * fv.w;
      }
#pragma unroll
      for (int i = 0; i < 4; i++) {
        float4 r = hv4[(size_t)n * CHW4 + (o0 + i) * 12 + hbp];
        acc[i].x += r.x; acc[i].y += r.y; acc[i].z += r.z; acc[i].w += r.w;
      }
    }

    if (!last) {
      if (t < 192) {
        float4* hn4 = (float4*)hvNext;
#pragma unroll
        for (int i = 0; i < 4; i++) {
          int pos = (o0 + i) * 12 + hbp;
          hn4[(size_t)n * CHW4 + pos] = acc[i];
          u32x2 ob2;
          ob2.x = pack_bf16(acc[i].x, acc[i].y);
          ob2.y = pack_bf16(acc[i].z, acc[i].w);
          mirOut[(size_t)n * CHW4 + pos] = ob2;
          float s4 = acc[i].x + acc[i].y + acc[i].z + acc[i].w;
          float q4 = acc[i].x * acc[i].x + acc[i].y * acc[i].y + acc[i].z * acc[i].z + acc[i].w * acc[i].w;
          atomicAdd(&bsum[o0 + i], s4);
          atomicAdd(&bsq[o0 + i], q4);
        }
      }
      __syncthreads();
      int r = n & 7;
      if (t < 64) atomicAdd(&statsNext[r * 128 + t], bsum[t]);
      else if (t < 128) atomicAdd(&statsNext[r * 128 + 64 + (t - 64)], bsq[t - 64]);
      __syncthreads();
    } else {
      __syncthreads();  // linear done reading fl
      if (t < 192) {
#pragma unroll
        for (int i = 0; i < 4; i++) fl4[(o0 + i) * 12 + hbp] = acc[i];
      }
      __syncthreads();
      if (t < 144) {
        int o = t / 12, hb2 = t % 12;
        float bias = a.ob[o];
        float4 acc2 = make_float4(bias, bias, bias, bias);
        for (int c2 = 0; c2 < 64; c2++) {
          float4 v = fl4[c2 * 12 + hb2];
          float mw = (v.x + v.y + v.z + v.w) * 0.25f;
          float wv = a.oW[c2 * 12 + o] * mw;
          acc2.x += wv * v.x; acc2.y += wv * v.y; acc2.z += wv * v.z; acc2.w += wv * v.w;
        }
        ((float4*)a.out)[(size_t)n * 144 + t] = acc2;
      }
      __syncthreads();
    }
  }
}

__global__ __launch_bounds__(256, 4) void fused_coop(KArgs a) {
  cg::grid_group g = cg::this_grid();
  do_init(a);
  __threadfence();
  g.sync();
  do_layer(a, 0);
  __threadfence();
  g.sync();
  do_layer(a, 1);
  __threadfence();
  g.sync();
  do_layer(a, 2);
}

// non-cooperative fallback (stream ordering replaces grid.sync)
__global__ __launch_bounds__(256, 4) void init_k(KArgs a) { do_init(a); }
__global__ __launch_bounds__(256, 4) void layer0_k(KArgs a) { do_layer(a, 0); }
__global__ __launch_bounds__(256, 4) void layer1_k(KArgs a) { do_layer(a, 1); }
__global__ __launch_bounds__(256, 4) void layer2_k(KArgs a) { do_layer(a, 2); }

extern "C" void kernel_launch(void* const* d_in, const int* in_sizes, int n_in,
                              void* d_out, int out_size, void* d_ws, size_t ws_size,
                              hipStream_t stream) {
  const float* node_feats = (const float*)d_in[0];
  const float* edge_feats = (const float*)d_in[1];
  const int* src = (const int*)d_in[2];
  const int* dst = (const int*)d_in[3];
  const float* bn_gamma = (const float*)d_in[4];
  const float* bn_beta = (const float*)d_in[5];
  const float* gen_W = (const float*)d_in[6];
  const float* gen_b = (const float*)d_in[7];
  const float* out_W = (const float*)d_in[8];
  const float* out_b = (const float*)d_in[9];
  float* out = (float*)d_out;

  char* ws = (char*)d_ws;
  float* hvA = (float*)ws;                        // 61,440,000 B
  float* hvB = (float*)(ws + 61440000);           // 61,440,000 B
  u32x2* hvbA = (u32x2*)(ws + 122880000);         // 30,720,000 B (bf16 raw hv)
  u32x2* hvbB = (u32x2*)(ws + 153600000);         // 30,720,000 B
  u32x2* heb = (u32x2*)(ws + 184320000);          // 307,200,000 B (bf16 he, CSR order)
  float* statsN = (float*)(ws + 491520000);       // 12,288 B (3 layers x 8 replicas x 128)
  int* cnt = (int*)(ws + 491532288);              // 20,000 B (contiguous with statsN)
  int* off = (int*)(ws + 491552288);              // 20,004 B
  int* cur = (int*)(ws + 491572292);              // 20,000 B
  int* eids = (int*)(ws + 491592292);             // 200,000 B
  int* srcs = (int*)(ws + 491792292);             // 200,000 B

  hipMemsetAsync(statsN, 0, 12288 + 20000, stream);  // statsN + cnt in one memset
  hist_kernel<<<(NE + 255) / 256, 256, 0, stream>>>(dst, cnt);
  scan_kernel<<<1, 256, 0, stream>>>(cnt, off, cur);
  scatter_kernel<<<(NE + 255) / 256, 256, 0, stream>>>(dst, src, cur, eids, srcs);

  KArgs ka;
  ka.hv0 = node_feats;
  ka.he = edge_feats;
  ka.srcs = srcs;
  ka.eids = eids;
  ka.off = off;
  ka.gamma = bn_gamma;
  ka.beta = bn_beta;
  ka.Wg = gen_W;
  ka.bg = gen_b;
  ka.oW = out_W;
  ka.ob = out_b;
  ka.hvA = hvA;
  ka.hvB = hvB;
  ka.hvbA = hvbA;
  ka.hvbB = hvbB;
  ka.heb = heb;
  ka.statsN = statsN;
  ka.out = out;

  int maxBlk = 0;
  hipError_t qe = hipOccupancyMaxActiveBlocksPerMultiprocessor(
      &maxBlk, reinterpret_cast<const void*>(fused_coop), 256, 0);
  if (qe == hipSuccess && maxBlk >= 1) {
    int grid = maxBlk * 256;  // 256 CUs on MI355X
    if (grid > 1024) grid = 1024;
    void* params[] = {&ka};
    hipLaunchCooperativeKernel((const void*)fused_coop, dim3(grid), dim3(256), params, 0, stream);
  } else {
    init_k<<<1024, 256, 0, stream>>>(ka);
    layer0_k<<<1024, 256, 0, stream>>>(ka);
    layer1_k<<<1024, 256, 0, stream>>>(ka);
    layer2_k<<<1024, 256, 0, stream>>>(ka);
  }
}

// Round 10
// 1680.768 us; speedup vs baseline: 1.0055x; 1.0055x over previous
//
#include <hip/hip_runtime.h>
#include <hip/hip_cooperative_groups.h>
#include <float.h>

namespace cg = cooperative_groups;

#define NN 5000
#define NE 50000
#define CHW4 768       // float4 units per node row
#define MAXD 64

typedef float f32x4 __attribute__((ext_vector_type(4)));
typedef unsigned int u32x2 __attribute__((ext_vector_type(2)));

__device__ __forceinline__ unsigned int pack_bf16(float a, float b) {
  unsigned int ua = __float_as_uint(a), ub = __float_as_uint(b);
  ua = (ua + 0x7FFFu + ((ua >> 16) & 1u)) >> 16;
  ub = (ub + 0x7FFFu + ((ub >> 16) & 1u)) & 0xFFFF0000u;
  return ua | ub;
}
__device__ __forceinline__ float bf_lo(unsigned int u) { return __uint_as_float(u << 16); }
__device__ __forceinline__ float bf_hi(unsigned int u) { return __uint_as_float(u & 0xFFFF0000u); }

// ---------------- CSR build ----------------
__global__ void hist_kernel(const int* __restrict__ dst, int* __restrict__ cnt) {
  int e = blockIdx.x * 256 + threadIdx.x;
  if (e < NE) atomicAdd(&cnt[dst[e]], 1);
}

__global__ void scan_kernel(const int* __restrict__ cnt, int* __restrict__ off, int* __restrict__ cur) {
  __shared__ int tsum[256];
  int t = threadIdx.x;
  constexpr int PER = 20;
  int base = t * PER;
  int vals[PER];
  int local = 0;
#pragma unroll
  for (int i = 0; i < PER; i++) {
    int idx = base + i;
    int v = (idx < NN) ? cnt[idx] : 0;
    vals[i] = local;
    local += v;
  }
  tsum[t] = local;
  __syncthreads();
  for (int o = 1; o < 256; o <<= 1) {
    int v = (t >= o) ? tsum[t - o] : 0;
    __syncthreads();
    tsum[t] += v;
    __syncthreads();
  }
  int excl = (t == 0) ? 0 : tsum[t - 1];
#pragma unroll
  for (int i = 0; i < PER; i++) {
    int idx = base + i;
    if (idx < NN) {
      int o2 = excl + vals[i];
      off[idx] = o2;
      cur[idx] = o2;
    }
  }
  if (t == 255) off[NN] = excl + local;
}

__global__ void scatter_kernel(const int* __restrict__ dst, const int* __restrict__ src,
                               int* __restrict__ cur, int* __restrict__ eids, int* __restrict__ srcs) {
  int e = blockIdx.x * 256 + threadIdx.x;
  if (e < NE) {
    int p = atomicAdd(&cur[dst[e]], 1);
    eids[p] = e;
    srcs[p] = src[e];
  }
}

// ---------------- fused bodies ----------------
struct KArgs {
  const float* hv0;
  const float* he;
  const int* srcs;
  const int* eids;
  const int* off;
  const float* gamma;   // [3][64]
  const float* beta;    // [3][64]
  const float* Wg;      // [3][64][64]
  const float* bg;      // [3][64]
  const float* oW;      // [64][12]
  const float* ob;      // [12]
  float* hvA;
  float* hvB;
  u32x2* hvbA;
  u32x2* hvbB;
  u32x2* heb;
  float* statsN;        // [3][8][128]
  float* out;
};

__device__ __forceinline__ void do_init(const KArgs& a) {
  __shared__ float ibsum[64], ibsq[64];
  int t = threadIdx.x;
  const float4* hv4 = (const float4*)a.hv0;
  for (int n = blockIdx.x; n < NN; n += gridDim.x) {
    if (t < 64) {
      ibsum[t] = 0.f;
      ibsq[t] = 0.f;
    }
    __syncthreads();
#pragma unroll
    for (int j = 0; j < 3; j++) {
      int q = t + j * 256;
      int c = q / 12;
      float4 v = hv4[(size_t)n * CHW4 + q];
      u32x2 o;
      o.x = pack_bf16(v.x, v.y);
      o.y = pack_bf16(v.z, v.w);
      a.hvbA[(size_t)n * CHW4 + q] = o;
      atomicAdd(&ibsum[c], v.x + v.y + v.z + v.w);
      atomicAdd(&ibsq[c], v.x * v.x + v.y * v.y + v.z * v.z + v.w * v.w);
    }
    __syncthreads();
    int r = n & 7;
    if (t < 64) atomicAdd(&a.statsN[r * 128 + t], ibsum[t]);
    else if (t < 128) atomicAdd(&a.statsN[r * 128 + 64 + (t - 64)], ibsq[t - 64]);
    __syncthreads();
  }
}

__device__ __forceinline__ void do_layer(const KArgs& a, int l) {
  __shared__ float fl[3072];
  __shared__ float scl[64], shl[64];
  __shared__ int sS[MAXD], sE[MAXD];
  __shared__ float bsum[64], bsq[64];

  int t = threadIdx.x;
  const float* hvPrev = (l == 0) ? a.hv0 : (l == 1 ? a.hvA : a.hvB);
  float* hvNext = (l == 0) ? a.hvA : a.hvB;
  const u32x2* mirIn = (l & 1) ? a.hvbB : a.hvbA;
  u32x2* mirOut = (l & 1) ? a.hvbA : a.hvbB;
  float* statsNext = a.statsN + (l + 1) * 1024;
  const float* WgL = a.Wg + l * 4096;
  const float* bgL = a.bg + l * 64;
  const bool first = (l == 0), last = (l == 2);

  // per-block BN finalize (statsN complete after previous grid sync)
  if (t < 64) {
    const float* sN = a.statsN + l * 1024;
    float s = 0.f, q = 0.f;
#pragma unroll
    for (int r = 0; r < 8; r++) {
      s += sN[r * 128 + t];
      q += sN[r * 128 + 64 + t];
    }
    const float inv = 1.f / 240000.f;
    float mu = s * inv;
    float var = q * inv - mu * mu;
    float scale = a.gamma[l * 64 + t] * rsqrtf(var + 1e-5f);
    scl[t] = scale;
    shl[t] = a.beta[l * 64 + t] - mu * scale;
  }
  __syncthreads();

  const float4* hv4 = (const float4*)hvPrev;
  const f32x4* heV = (const f32x4*)a.he;
  const float4* w4 = (const float4*)WgL;
  float4* fl4 = (float4*)fl;

  for (int n = blockIdx.x; n < NN; n += gridDim.x) {
    if (!last && t < 64) {
      bsum[t] = 0.f;
      bsq[t] = 0.f;
    }

    float scv[3], shv[3], h1[12];
#pragma unroll
    for (int j = 0; j < 3; j++) {
      int q = t + j * 256;
      int c = q / 12;
      scv[j] = scl[c];
      shv[j] = shl[c];
      float4 v = hv4[(size_t)n * CHW4 + q];
      h1[4 * j + 0] = fmaxf(v.x * scv[j] + shv[j], 0.f);
      h1[4 * j + 1] = fmaxf(v.y * scv[j] + shv[j], 0.f);
      h1[4 * j + 2] = fmaxf(v.z * scv[j] + shv[j], 0.f);
      h1[4 * j + 3] = fmaxf(v.w * scv[j] + shv[j], 0.f);
    }

    float S[12], T[12];
#pragma unroll
    for (int i = 0; i < 12; i++) {
      S[i] = 0.f;
      T[i] = 0.f;
    }

    int e0 = a.off[n], d = a.off[n + 1] - e0;
    for (int base = 0; base < d; base += MAXD) {
      int cnt = min(MAXD, d - base);
      __syncthreads();
      if (t < cnt) {
        sS[t] = a.srcs[e0 + base + t];
        if (first) sE[t] = a.eids[e0 + base + t];
      }
      __syncthreads();
      if (first) {
#pragma unroll 2
        for (int k = 0; k < cnt; k++) {
          size_t hb = (size_t)sS[k] * CHW4;
          size_t pbq = (size_t)(e0 + base + k) * CHW4;
#pragma unroll
          for (int j = 0; j < 3; j++) {
            int q = t + j * 256;
            u32x2 hg = mirIn[hb + q];
            float hgf[4];
            hgf[0] = fmaxf(bf_lo(hg.x) * scv[j] + shv[j], 0.f);
            hgf[1] = fmaxf(bf_hi(hg.x) * scv[j] + shv[j], 0.f);
            hgf[2] = fmaxf(bf_lo(hg.y) * scv[j] + shv[j], 0.f);
            hgf[3] = fmaxf(bf_hi(hg.y) * scv[j] + shv[j], 0.f);
            f32x4 b = __builtin_nontemporal_load(&heV[(size_t)sE[k] * CHW4 + q]);
            u32x2 o;
            o.x = pack_bf16(b.x, b.y);
            o.y = pack_bf16(b.z, b.w);
            __builtin_nontemporal_store(o, &a.heb[pbq + q]);
            float hef[4] = {b.x, b.y, b.z, b.w};
#pragma unroll
            for (int u = 0; u < 4; u++) {
              float m = fmaxf(hgf[u] + hef[u], 0.f) + 1e-7f;
              float e = __expf(m);  // shift-free softmax: m bounded
              int idx = j * 4 + u;
              S[idx] += e;
              T[idx] += e * m;
            }
          }
        }
      } else {
#pragma unroll 2
        for (int k = 0; k < cnt; k++) {
          size_t hb = (size_t)sS[k] * CHW4;
          size_t pbq = (size_t)(e0 + base + k) * CHW4;
#pragma unroll
          for (int j = 0; j < 3; j++) {
            int q = t + j * 256;
            u32x2 hg = mirIn[hb + q];
            float hgf[4];
            hgf[0] = fmaxf(bf_lo(hg.x) * scv[j] + shv[j], 0.f);
            hgf[1] = fmaxf(bf_hi(hg.x) * scv[j] + shv[j], 0.f);
            hgf[2] = fmaxf(bf_lo(hg.y) * scv[j] + shv[j], 0.f);
            hgf[3] = fmaxf(bf_hi(hg.y) * scv[j] + shv[j], 0.f);
            u32x2 bb = __builtin_nontemporal_load(&a.heb[pbq + q]);
            float hef[4] = {bf_lo(bb.x), bf_hi(bb.x), bf_lo(bb.y), bf_hi(bb.y)};
#pragma unroll
            for (int u = 0; u < 4; u++) {
              float m = fmaxf(hgf[u] + hef[u], 0.f) + 1e-7f;
              float e = __expf(m);
              int idx = j * 4 + u;
              S[idx] += e;
              T[idx] += e * m;
            }
          }
        }
      }
    }

    bool hasE = d > 0;
#pragma unroll
    for (int j = 0; j < 3; j++) {
      int q = t + j * 256, idx = 4 * j;
      float4 f;
      f.x = h1[idx + 0] + (hasE ? T[idx + 0] / S[idx + 0] : 0.f);
      f.y = h1[idx + 1] + (hasE ? T[idx + 1] / S[idx + 1] : 0.f);
      f.z = h1[idx + 2] + (hasE ? T[idx + 2] / S[idx + 2] : 0.f);
      f.w = h1[idx + 3] + (hasE ? T[idx + 3] / S[idx + 3] : 0.f);
      fl4[q] = f;
    }
    __syncthreads();

    // linear: 192 threads, 4 out-channels x 1 h-position each; W from global (L1-resident)
    int o0 = (t / 12) * 4, hbp = t % 12;
    float4 acc[4];
    if (t < 192) {
#pragma unroll
      for (int i = 0; i < 4; i++) {
        float bv = bgL[o0 + i];
        acc[i] = make_float4(bv, bv, bv, bv);
      }
      int widx = o0 >> 2;
      for (int c2 = 0; c2 < 64; c2++) {
        float4 fv = fl4[c2 * 12 + hbp];
        float4 wv = w4[c2 * 16 + widx];
        acc[0].x += wv.x * fv.x; acc[0].y += wv.x * fv.y; acc[0].z += wv.x * fv.z; acc[0].w += wv.x * fv.w;
        acc[1].x += wv.y * fv.x; acc[1].y += wv.y * fv.y; acc[1].z += wv.y * fv.z; acc[1].w += wv.y * fv.w;
        acc[2].x += wv.z * fv.x; acc[2].y += wv.z * fv.y; acc[2].z += wv.z * fv.z; acc[2].w += wv.z * fv.w;
        acc[3].x += wv.w * fv.x; acc[3].y += wv.w * fv.y; acc[3].z += wv.w * fv.z; acc[3].w += wv.w * fv.w;
      }
#pragma unroll
      for (int i = 0; i < 4; i++) {
        float4 r = hv4[(size_t)n * CHW4 + (o0 + i) * 12 + hbp];
        acc[i].x += r.x; acc[i].y += r.y; acc[i].z += r.z; acc[i].w += r.w;
      }
    }

    if (!last) {
      if (t < 192) {
        float4* hn4 = (float4*)hvNext;
#pragma unroll
        for (int i = 0; i < 4; i++) {
          int pos = (o0 + i) * 12 + hbp;
          hn4[(size_t)n * CHW4 + pos] = acc[i];
          u32x2 ob2;
          ob2.x = pack_bf16(acc[i].x, acc[i].y);
          ob2.y = pack_bf16(acc[i].z, acc[i].w);
          mirOut[(size_t)n * CHW4 + pos] = ob2;
          float s4 = acc[i].x + acc[i].y + acc[i].z + acc[i].w;
          float q4 = acc[i].x * acc[i].x + acc[i].y * acc[i].y + acc[i].z * acc[i].z + acc[i].w * acc[i].w;
          atomicAdd(&bsum[o0 + i], s4);
          atomicAdd(&bsq[o0 + i], q4);
        }
      }
      __syncthreads();
      int r = n & 7;
      if (t < 64) atomicAdd(&statsNext[r * 128 + t], bsum[t]);
      else if (t < 128) atomicAdd(&statsNext[r * 128 + 64 + (t - 64)], bsq[t - 64]);
      __syncthreads();
    } else {
      __syncthreads();  // linear done reading fl
      if (t < 192) {
#pragma unroll
        for (int i = 0; i < 4; i++) fl4[(o0 + i) * 12 + hbp] = acc[i];
      }
      __syncthreads();
      if (t < 144) {
        int o = t / 12, hb2 = t % 12;
        float bias = a.ob[o];
        float4 acc2 = make_float4(bias, bias, bias, bias);
        for (int c2 = 0; c2 < 64; c2++) {
          float4 v = fl4[c2 * 12 + hb2];
          float mw = (v.x + v.y + v.z + v.w) * 0.25f;
          float wv = a.oW[c2 * 12 + o] * mw;
          acc2.x += wv * v.x; acc2.y += wv * v.y; acc2.z += wv * v.z; acc2.w += wv * v.w;
        }
        ((float4*)a.out)[(size_t)n * 144 + t] = acc2;
      }
      __syncthreads();
    }
  }
}

__global__ __launch_bounds__(256) void fused_coop(KArgs a) {
  cg::grid_group g = cg::this_grid();
  do_init(a);
  __threadfence();
  g.sync();
  do_layer(a, 0);
  __threadfence();
  g.sync();
  do_layer(a, 1);
  __threadfence();
  g.sync();
  do_layer(a, 2);
}

// non-cooperative fallback (stream ordering replaces grid.sync)
__global__ __launch_bounds__(256) void init_k(KArgs a) { do_init(a); }
__global__ __launch_bounds__(256) void layer0_k(KArgs a) { do_layer(a, 0); }
__global__ __launch_bounds__(256) void layer1_k(KArgs a) { do_layer(a, 1); }
__global__ __launch_bounds__(256) void layer2_k(KArgs a) { do_layer(a, 2); }

extern "C" void kernel_launch(void* const* d_in, const int* in_sizes, int n_in,
                              void* d_out, int out_size, void* d_ws, size_t ws_size,
                              hipStream_t stream) {
  const float* node_feats = (const float*)d_in[0];
  const float* edge_feats = (const float*)d_in[1];
  const int* src = (const int*)d_in[2];
  const int* dst = (const int*)d_in[3];
  const float* bn_gamma = (const float*)d_in[4];
  const float* bn_beta = (const float*)d_in[5];
  const float* gen_W = (const float*)d_in[6];
  const float* gen_b = (const float*)d_in[7];
  const float* out_W = (const float*)d_in[8];
  const float* out_b = (const float*)d_in[9];
  float* out = (float*)d_out;

  char* ws = (char*)d_ws;
  float* hvA = (float*)ws;                        // 61,440,000 B
  float* hvB = (float*)(ws + 61440000);           // 61,440,000 B
  u32x2* hvbA = (u32x2*)(ws + 122880000);         // 30,720,000 B (bf16 raw hv)
  u32x2* hvbB = (u32x2*)(ws + 153600000);         // 30,720,000 B
  u32x2* heb = (u32x2*)(ws + 184320000);          // 307,200,000 B (bf16 he, CSR order)
  float* statsN = (float*)(ws + 491520000);       // 12,288 B (3 layers x 8 replicas x 128)
  int* cnt = (int*)(ws + 491532288);              // 20,000 B (contiguous with statsN)
  int* off = (int*)(ws + 491552288);              // 20,004 B
  int* cur = (int*)(ws + 491572292);              // 20,000 B
  int* eids = (int*)(ws + 491592292);             // 200,000 B
  int* srcs = (int*)(ws + 491792292);             // 200,000 B

  hipMemsetAsync(statsN, 0, 12288 + 20000, stream);  // statsN + cnt in one memset
  hist_kernel<<<(NE + 255) / 256, 256, 0, stream>>>(dst, cnt);
  scan_kernel<<<1, 256, 0, stream>>>(cnt, off, cur);
  scatter_kernel<<<(NE + 255) / 256, 256, 0, stream>>>(dst, src, cur, eids, srcs);

  KArgs ka;
  ka.hv0 = node_feats;
  ka.he = edge_feats;
  ka.srcs = srcs;
  ka.eids = eids;
  ka.off = off;
  ka.gamma = bn_gamma;
  ka.beta = bn_beta;
  ka.Wg = gen_W;
  ka.bg = gen_b;
  ka.oW = out_W;
  ka.ob = out_b;
  ka.hvA = hvA;
  ka.hvB = hvB;
  ka.hvbA = hvbA;
  ka.hvbB = hvbB;
  ka.heb = heb;
  ka.statsN = statsN;
  ka.out = out;

  int maxBlk = 0;
  hipError_t qe = hipOccupancyMaxActiveBlocksPerMultiprocessor(
      &maxBlk, reinterpret_cast<const void*>(fused_coop), 256, 0);
  if (qe == hipSuccess && maxBlk >= 1) {
    int grid = maxBlk * 256;  // 256 CUs on MI355X
    if (grid > 2048) grid = 2048;
    void* params[] = {&ka};
    hipLaunchCooperativeKernel((const void*)fused_coop, dim3(grid), dim3(256), params, 0, stream);
  } else {
    init_k<<<1024, 256, 0, stream>>>(ka);
    layer0_k<<<1024, 256, 0, stream>>>(ka);
    layer1_k<<<1024, 256, 0, stream>>>(ka);
    layer2_k<<<1024, 256, 0, stream>>>(ka);
  }
}

// Round 11
// 591.236 us; speedup vs baseline: 2.8585x; 2.8428x over previous
//
#include <hip/hip_runtime.h>
#include <float.h>

#define NN 5000
#define NE 50000
#define C 64
#define CHW4 768       // float4 units per node row

typedef float f32x4 __attribute__((ext_vector_type(4)));
typedef unsigned int u32x2 __attribute__((ext_vector_type(2)));

__device__ __forceinline__ unsigned int pack_bf16(float a, float b) {
  unsigned int ua = __float_as_uint(a), ub = __float_as_uint(b);
  ua = (ua + 0x7FFFu + ((ua >> 16) & 1u)) >> 16;
  ub = (ub + 0x7FFFu + ((ub >> 16) & 1u)) & 0xFFFF0000u;
  return ua | ub;
}
__device__ __forceinline__ float bf_lo(unsigned int u) { return __uint_as_float(u << 16); }
__device__ __forceinline__ float bf_hi(unsigned int u) { return __uint_as_float(u & 0xFFFF0000u); }

// ---------------- CSR build ----------------
__global__ void hist_kernel(const int* __restrict__ dst, int* __restrict__ cnt) {
  int e = blockIdx.x * 256 + threadIdx.x;
  if (e < NE) atomicAdd(&cnt[dst[e]], 1);
}

__global__ void scan_kernel(const int* __restrict__ cnt, int* __restrict__ off, int* __restrict__ cur) {
  __shared__ int tsum[256];
  int t = threadIdx.x;
  constexpr int PER = 20;
  int base = t * PER;
  int vals[PER];
  int local = 0;
#pragma unroll
  for (int i = 0; i < PER; i++) {
    int idx = base + i;
    int v = (idx < NN) ? cnt[idx] : 0;
    vals[i] = local;
    local += v;
  }
  tsum[t] = local;
  __syncthreads();
  for (int o = 1; o < 256; o <<= 1) {
    int v = (t >= o) ? tsum[t - o] : 0;
    __syncthreads();
    tsum[t] += v;
    __syncthreads();
  }
  int excl = (t == 0) ? 0 : tsum[t - 1];
#pragma unroll
  for (int i = 0; i < PER; i++) {
    int idx = base + i;
    if (idx < NN) {
      int o2 = excl + vals[i];
      off[idx] = o2;
      cur[idx] = o2;
    }
  }
  if (t == 255) off[NN] = excl + local;
}

__global__ void scatter_kernel(const int* __restrict__ dst, const int* __restrict__ src,
                               int* __restrict__ cur, int* __restrict__ eids, int* __restrict__ srcs) {
  int e = blockIdx.x * 256 + threadIdx.x;
  if (e < NE) {
    int p = atomicAdd(&cur[dst[e]], 1);
    eids[p] = e;
    srcs[p] = src[e];
  }
}

// ---------------- init: node_feats -> bf16 mirror + layer-0 BN stats ----------------
__global__ __launch_bounds__(256) void init_kernel(const float* __restrict__ hv,
                                                   u32x2* __restrict__ hvb,
                                                   float* __restrict__ statsN) {
  __shared__ float bsum[64], bsq[64];
  int n = blockIdx.x, t = threadIdx.x;
  if (t < 64) {
    bsum[t] = 0.f;
    bsq[t] = 0.f;
  }
  __syncthreads();
  const float4* hv4 = (const float4*)hv;
#pragma unroll
  for (int j = 0; j < 3; j++) {
    int q = t + j * 256;
    int c = q / 12;
    float4 v = hv4[(size_t)n * CHW4 + q];
    u32x2 o;
    o.x = pack_bf16(v.x, v.y);
    o.y = pack_bf16(v.z, v.w);
    hvb[(size_t)n * CHW4 + q] = o;
    atomicAdd(&bsum[c], v.x + v.y + v.z + v.w);
    atomicAdd(&bsq[c], v.x * v.x + v.y * v.y + v.z * v.z + v.w * v.w);
  }
  __syncthreads();
  int r = n & 7;
  if (t < 64) atomicAdd(&statsN[r * 128 + t], bsum[t]);
  else if (t < 128) atomicAdd(&statsN[r * 128 + 64 + (t - 64)], bsq[t - 64]);
}

// ---------------- Fused GENConv layer ----------------
// One block per node; per-block BN finalize in prologue; barrier-free edge loop
// (wave-uniform srcs/eids loads, L1-broadcast); bf16 mirror gathers; nt-streamed he.
template <bool FIRST, bool LAST>
__global__ __launch_bounds__(256) void aggregate_kernel(
    const float* __restrict__ hv, const float* __restrict__ he,
    const u32x2* __restrict__ mirIn, u32x2* __restrict__ mirOut,
    u32x2* __restrict__ heb,
    const int* __restrict__ srcs, const int* __restrict__ eids, const int* __restrict__ off,
    const float* __restrict__ Wg, const float* __restrict__ bg,
    const float* __restrict__ gamma, const float* __restrict__ beta,
    const float* __restrict__ statsL,   // this layer's stats (8 replicas x 128)
    float* __restrict__ hvNext, float* __restrict__ statsNext,
    const float* __restrict__ oW, const float* __restrict__ ob,
    float* __restrict__ out) {
  __shared__ float fl[3072];
  __shared__ float scl[64], shl[64];
  __shared__ float bsum[64], bsq[64];

  int n = blockIdx.x, t = threadIdx.x;

  // per-block BN finalize (statsL complete via stream ordering)
  if (t < 64) {
    float s = 0.f, q = 0.f;
#pragma unroll
    for (int r = 0; r < 8; r++) {
      s += statsL[r * 128 + t];
      q += statsL[r * 128 + 64 + t];
    }
    const float inv = 1.f / 240000.f;
    float mu = s * inv;
    float var = q * inv - mu * mu;
    float scale = gamma[t] * rsqrtf(var + 1e-5f);
    scl[t] = scale;
    shl[t] = beta[t] - mu * scale;
    if (!LAST) {
      bsum[t] = 0.f;
      bsq[t] = 0.f;
    }
  }
  __syncthreads();

  const float4* hv4 = (const float4*)hv;
  const f32x4* heV = (const f32x4*)he;
  const float4* w4 = (const float4*)Wg;
  float4* fl4 = (float4*)fl;

  float scv[3], shv[3], h1[12];
#pragma unroll
  for (int j = 0; j < 3; j++) {
    int q = t + j * 256;
    int c = q / 12;
    scv[j] = scl[c];
    shv[j] = shl[c];
    float4 v = hv4[(size_t)n * CHW4 + q];
    h1[4 * j + 0] = fmaxf(v.x * scv[j] + shv[j], 0.f);
    h1[4 * j + 1] = fmaxf(v.y * scv[j] + shv[j], 0.f);
    h1[4 * j + 2] = fmaxf(v.z * scv[j] + shv[j], 0.f);
    h1[4 * j + 3] = fmaxf(v.w * scv[j] + shv[j], 0.f);
  }

  float S[12], T[12];
#pragma unroll
  for (int i = 0; i < 12; i++) {
    S[i] = 0.f;
    T[i] = 0.f;
  }

  int e0 = off[n], d = off[n + 1] - e0;
  // barrier-free edge loop: srcs/eids via wave-uniform loads (L1 broadcast)
#pragma unroll 2
  for (int k = 0; k < d; k++) {
    int sK = srcs[e0 + k];
    size_t hb = (size_t)sK * CHW4;
    size_t pbq = (size_t)(e0 + k) * CHW4;
    if (FIRST) {
      int eK = eids[e0 + k];
#pragma unroll
      for (int j = 0; j < 3; j++) {
        int q = t + j * 256;
        u32x2 hg = mirIn[hb + q];
        float hgf[4];
        hgf[0] = fmaxf(bf_lo(hg.x) * scv[j] + shv[j], 0.f);
        hgf[1] = fmaxf(bf_hi(hg.x) * scv[j] + shv[j], 0.f);
        hgf[2] = fmaxf(bf_lo(hg.y) * scv[j] + shv[j], 0.f);
        hgf[3] = fmaxf(bf_hi(hg.y) * scv[j] + shv[j], 0.f);
        f32x4 b = __builtin_nontemporal_load(&heV[(size_t)eK * CHW4 + q]);
        u32x2 o;
        o.x = pack_bf16(b.x, b.y);
        o.y = pack_bf16(b.z, b.w);
        __builtin_nontemporal_store(o, &heb[pbq + q]);
        float hef[4] = {b.x, b.y, b.z, b.w};
#pragma unroll
        for (int u = 0; u < 4; u++) {
          float m = fmaxf(hgf[u] + hef[u], 0.f) + 1e-7f;
          float e = __expf(m);  // shift-free softmax: m bounded
          int idx = j * 4 + u;
          S[idx] += e;
          T[idx] += e * m;
        }
      }
    } else {
#pragma unroll
      for (int j = 0; j < 3; j++) {
        int q = t + j * 256;
        u32x2 hg = mirIn[hb + q];
        float hgf[4];
        hgf[0] = fmaxf(bf_lo(hg.x) * scv[j] + shv[j], 0.f);
        hgf[1] = fmaxf(bf_hi(hg.x) * scv[j] + shv[j], 0.f);
        hgf[2] = fmaxf(bf_lo(hg.y) * scv[j] + shv[j], 0.f);
        hgf[3] = fmaxf(bf_hi(hg.y) * scv[j] + shv[j], 0.f);
        u32x2 bb = __builtin_nontemporal_load(&heb[pbq + q]);
        float hef[4] = {bf_lo(bb.x), bf_hi(bb.x), bf_lo(bb.y), bf_hi(bb.y)};
#pragma unroll
        for (int u = 0; u < 4; u++) {
          float m = fmaxf(hgf[u] + hef[u], 0.f) + 1e-7f;
          float e = __expf(m);
          int idx = j * 4 + u;
          S[idx] += e;
          T[idx] += e * m;
        }
      }
    }
  }

  bool hasE = d > 0;
#pragma unroll
  for (int j = 0; j < 3; j++) {
    int q = t + j * 256, idx = 4 * j;
    float4 f;
    f.x = h1[idx + 0] + (hasE ? T[idx + 0] / S[idx + 0] : 0.f);
    f.y = h1[idx + 1] + (hasE ? T[idx + 1] / S[idx + 1] : 0.f);
    f.z = h1[idx + 2] + (hasE ? T[idx + 2] / S[idx + 2] : 0.f);
    f.w = h1[idx + 3] + (hasE ? T[idx + 3] / S[idx + 3] : 0.f);
    fl4[q] = f;
  }
  __syncthreads();

  // linear: 192 threads, 4 out-channels x 1 h-position each; W from global (L1-resident)
  int o0 = (t / 12) * 4, hbp = t % 12;
  float4 acc[4];
  if (t < 192) {
#pragma unroll
    for (int i = 0; i < 4; i++) {
      float bv = bg[o0 + i];
      acc[i] = make_float4(bv, bv, bv, bv);
    }
    int widx = o0 >> 2;
    for (int c2 = 0; c2 < 64; c2++) {
      float4 fv = fl4[c2 * 12 + hbp];
      float4 wv = w4[c2 * 16 + widx];
      acc[0].x += wv.x * fv.x; acc[0].y += wv.x * fv.y; acc[0].z += wv.x * fv.z; acc[0].w += wv.x * fv.w;
      acc[1].x += wv.y * fv.x; acc[1].y += wv.y * fv.y; acc[1].z += wv.y * fv.z; acc[1].w += wv.y * fv.w;
      acc[2].x += wv.z * fv.x; acc[2].y += wv.z * fv.y; acc[2].z += wv.z * fv.z; acc[2].w += wv.z * fv.w;
      acc[3].x += wv.w * fv.x; acc[3].y += wv.w * fv.y; acc[3].z += wv.w * fv.z; acc[3].w += wv.w * fv.w;
    }
#pragma unroll
    for (int i = 0; i < 4; i++) {
      float4 r = hv4[(size_t)n * CHW4 + (o0 + i) * 12 + hbp];
      acc[i].x += r.x; acc[i].y += r.y; acc[i].z += r.z; acc[i].w += r.w;
    }
  }

  if constexpr (!LAST) {
    if (t < 192) {
      float4* hn4 = (float4*)hvNext;
#pragma unroll
      for (int i = 0; i < 4; i++) {
        int pos = (o0 + i) * 12 + hbp;
        hn4[(size_t)n * CHW4 + pos] = acc[i];
        u32x2 ob2;
        ob2.x = pack_bf16(acc[i].x, acc[i].y);
        ob2.y = pack_bf16(acc[i].z, acc[i].w);
        mirOut[(size_t)n * CHW4 + pos] = ob2;
        float s4 = acc[i].x + acc[i].y + acc[i].z + acc[i].w;
        float q4 = acc[i].x * acc[i].x + acc[i].y * acc[i].y + acc[i].z * acc[i].z + acc[i].w * acc[i].w;
        atomicAdd(&bsum[o0 + i], s4);
        atomicAdd(&bsq[o0 + i], q4);
      }
    }
    __syncthreads();
    int r = n & 7;
    if (t < 64) atomicAdd(&statsNext[r * 128 + t], bsum[t]);
    else if (t < 128) atomicAdd(&statsNext[r * 128 + 64 + (t - 64)], bsq[t - 64]);
  } else {
    __syncthreads();  // linear done reading fl
    if (t < 192) {
#pragma unroll
      for (int i = 0; i < 4; i++) fl4[(o0 + i) * 12 + hbp] = acc[i];
    }
    __syncthreads();
    if (t < 144) {
      int o = t / 12, hb2 = t % 12;
      float bias = ob[o];
      float4 acc2 = make_float4(bias, bias, bias, bias);
      for (int c2 = 0; c2 < 64; c2++) {
        float4 v = fl4[c2 * 12 + hb2];
        float mw = (v.x + v.y + v.z + v.w) * 0.25f;
        float wv = oW[c2 * 12 + o] * mw;
        acc2.x += wv * v.x; acc2.y += wv * v.y; acc2.z += wv * v.z; acc2.w += wv * v.w;
      }
      ((float4*)out)[(size_t)n * 144 + t] = acc2;
    }
  }
}

extern "C" void kernel_launch(void* const* d_in, const int* in_sizes, int n_in,
                              void* d_out, int out_size, void* d_ws, size_t ws_size,
                              hipStream_t stream) {
  const float* node_feats = (const float*)d_in[0];
  const float* edge_feats = (const float*)d_in[1];
  const int* src = (const int*)d_in[2];
  const int* dst = (const int*)d_in[3];
  const float* bn_gamma = (const float*)d_in[4];
  const float* bn_beta = (const float*)d_in[5];
  const float* gen_W = (const float*)d_in[6];
  const float* gen_b = (const float*)d_in[7];
  const float* out_W = (const float*)d_in[8];
  const float* out_b = (const float*)d_in[9];
  float* out = (float*)d_out;

  char* ws = (char*)d_ws;
  float* hvA = (float*)ws;                        // 61,440,000 B
  float* hvB = (float*)(ws + 61440000);           // 61,440,000 B
  u32x2* hvbA = (u32x2*)(ws + 122880000);         // 30,720,000 B (bf16 raw hv)
  u32x2* hvbB = (u32x2*)(ws + 153600000);         // 30,720,000 B
  u32x2* heb = (u32x2*)(ws + 184320000);          // 307,200,000 B (bf16 he, CSR order)
  float* statsN = (float*)(ws + 491520000);       // 12,288 B (3 layers x 8 replicas x 128)
  int* cnt = (int*)(ws + 491532288);              // 20,000 B (contiguous with statsN)
  int* off = (int*)(ws + 491552288);              // 20,004 B
  int* cur = (int*)(ws + 491572292);              // 20,000 B
  int* eids = (int*)(ws + 491592292);             // 200,000 B
  int* srcs = (int*)(ws + 491792292);             // 200,000 B

  hipMemsetAsync(statsN, 0, 12288 + 20000, stream);  // statsN + cnt in one memset
  hist_kernel<<<(NE + 255) / 256, 256, 0, stream>>>(dst, cnt);
  scan_kernel<<<1, 256, 0, stream>>>(cnt, off, cur);
  scatter_kernel<<<(NE + 255) / 256, 256, 0, stream>>>(dst, src, cur, eids, srcs);

  init_kernel<<<NN, 256, 0, stream>>>(node_feats, hvbA, statsN);

  // layer 0
  aggregate_kernel<true, false><<<NN, 256, 0, stream>>>(
      node_feats, edge_feats, hvbA, hvbB, heb, srcs, eids, off,
      gen_W, gen_b, bn_gamma, bn_beta, statsN,
      hvA, statsN + 1024, out_W, out_b, out);

  // layer 1
  aggregate_kernel<false, false><<<NN, 256, 0, stream>>>(
      hvA, edge_feats, hvbB, hvbA, heb, srcs, eids, off,
      gen_W + 4096, gen_b + 64, bn_gamma + 64, bn_beta + 64, statsN + 1024,
      hvB, statsN + 2048, out_W, out_b, out);

  // layer 2 (fused output)
  aggregate_kernel<false, true><<<NN, 256, 0, stream>>>(
      hvB, edge_feats, hvbA, hvbB, heb, srcs, eids, off,
      gen_W + 8192, gen_b + 128, bn_gamma + 128, bn_beta + 128, statsN + 2048,
      hvA, statsN, out_W, out_b, out);
}

// Round 12
// 574.118 us; speedup vs baseline: 2.9438x; 1.0298x over previous
//
#include <hip/hip_runtime.h>
#include <float.h>

#define NN 5000
#define NE 50000
#define C 64
#define CHW4 768       // float4 units per node row
#define SPLIT 25
#define NPS 200        // 5000/25
#define MAXD 64

typedef float f32x4 __attribute__((ext_vector_type(4)));
typedef unsigned int u32x2 __attribute__((ext_vector_type(2)));

__device__ __forceinline__ unsigned int pack_bf16(float a, float b) {
  unsigned int ua = __float_as_uint(a), ub = __float_as_uint(b);
  ua = (ua + 0x7FFFu + ((ua >> 16) & 1u)) >> 16;
  ub = (ub + 0x7FFFu + ((ub >> 16) & 1u)) & 0xFFFF0000u;
  return ua | ub;
}
__device__ __forceinline__ float bf_lo(unsigned int u) { return __uint_as_float(u << 16); }
__device__ __forceinline__ float bf_hi(unsigned int u) { return __uint_as_float(u & 0xFFFF0000u); }

// ---------------- CSR build ----------------
__global__ void hist_kernel(const int* __restrict__ dst, int* __restrict__ cnt) {
  int e = blockIdx.x * 256 + threadIdx.x;
  if (e < NE) atomicAdd(&cnt[dst[e]], 1);
}

__global__ void scan_kernel(const int* __restrict__ cnt, int* __restrict__ off, int* __restrict__ cur) {
  __shared__ int tsum[256];
  int t = threadIdx.x;
  constexpr int PER = 20;
  int base = t * PER;
  int vals[PER];
  int local = 0;
#pragma unroll
  for (int i = 0; i < PER; i++) {
    int idx = base + i;
    int v = (idx < NN) ? cnt[idx] : 0;
    vals[i] = local;
    local += v;
  }
  tsum[t] = local;
  __syncthreads();
  for (int o = 1; o < 256; o <<= 1) {
    int v = (t >= o) ? tsum[t - o] : 0;
    __syncthreads();
    tsum[t] += v;
    __syncthreads();
  }
  int excl = (t == 0) ? 0 : tsum[t - 1];
#pragma unroll
  for (int i = 0; i < PER; i++) {
    int idx = base + i;
    if (idx < NN) {
      int o2 = excl + vals[i];
      off[idx] = o2;
      cur[idx] = o2;
    }
  }
  if (t == 255) off[NN] = excl + local;
}

__global__ void scatter_kernel(const int* __restrict__ dst, const int* __restrict__ src,
                               int* __restrict__ cur, int* __restrict__ eids, int* __restrict__ srcs) {
  int e = blockIdx.x * 256 + threadIdx.x;
  if (e < NE) {
    int p = atomicAdd(&cur[dst[e]], 1);
    eids[p] = e;
    srcs[p] = src[e];
  }
}

// ---------------- BatchNorm stats (layer 0 only) ----------------
__global__ void bn_stats_kernel(const float* __restrict__ hv, float* __restrict__ statsN) {
  int c = blockIdx.x / SPLIT, s = blockIdx.x % SPLIT;
  int n0 = s * NPS;
  const float4* hv4 = (const float4*)hv;
  float sum = 0.f, ss = 0.f;
  for (int i = threadIdx.x; i < NPS * 12; i += 256) {
    int n = n0 + i / 12, p = i % 12;
    float4 v = hv4[(size_t)n * CHW4 + c * 12 + p];
    sum += v.x + v.y + v.z + v.w;
    ss += v.x * v.x + v.y * v.y + v.z * v.z + v.w * v.w;
  }
  __shared__ float rs[256], rq[256];
  rs[threadIdx.x] = sum;
  rq[threadIdx.x] = ss;
  __syncthreads();
  for (int o = 128; o > 0; o >>= 1) {
    if (threadIdx.x < o) {
      rs[threadIdx.x] += rs[threadIdx.x + o];
      rq[threadIdx.x] += rq[threadIdx.x + o];
    }
    __syncthreads();
  }
  if (threadIdx.x == 0) {
    int r = blockIdx.x & 7;
    atomicAdd(&statsN[r * 128 + c], rs[0]);
    atomicAdd(&statsN[r * 128 + 64 + c], rq[0]);
  }
}

__global__ void finalize2_kernel(const float* __restrict__ statsN, const float* __restrict__ gamma,
                                 const float* __restrict__ beta, float* __restrict__ sc,
                                 float* __restrict__ sh) {
  int c = threadIdx.x;
  if (c < C) {
    float s = 0.f, q = 0.f;
#pragma unroll
    for (int r = 0; r < 8; r++) {
      s += statsN[r * 128 + c];
      q += statsN[r * 128 + 64 + c];
    }
    const float inv = 1.f / 240000.f;
    float mu = s * inv;
    float var = q * inv - mu * mu;
    float scale = gamma[c] * rsqrtf(var + 1e-5f);
    sc[c] = scale;
    sh[c] = beta[c] - mu * scale;
  }
}

// ---------------- h1 = BN+ReLU(hv) in bf16 (coalesced pass) ----------------
__global__ __launch_bounds__(256) void h1_kernel(const float* __restrict__ hv,
                                                 const float* __restrict__ sc,
                                                 const float* __restrict__ sh,
                                                 u32x2* __restrict__ h1g) {
  int idx = blockIdx.x * 256 + threadIdx.x;  // float4 index, < NN*768
  int q = idx % CHW4;
  int c = q / 12;
  float s = sc[c], b = sh[c];
  float4 v = ((const float4*)hv)[idx];
  float x0 = fmaxf(v.x * s + b, 0.f);
  float x1 = fmaxf(v.y * s + b, 0.f);
  float x2 = fmaxf(v.z * s + b, 0.f);
  float x3 = fmaxf(v.w * s + b, 0.f);
  u32x2 o;
  o.x = pack_bf16(x0, x1);
  o.y = pack_bf16(x2, x3);
  h1g[idx] = o;
}

// ---------------- Fused GENConv layer (software-pipelined edge loop) ----------------
template <bool FIRST, bool LAST>
__global__ __launch_bounds__(256) void aggregate_kernel(
    const float* __restrict__ hv, const float* __restrict__ he,
    const u32x2* __restrict__ h1g, u32x2* __restrict__ heb,
    const int* __restrict__ srcs, const int* __restrict__ eids, const int* __restrict__ off,
    const float* __restrict__ Wg, const float* __restrict__ bg,
    const float* __restrict__ sc, const float* __restrict__ sh,
    float* __restrict__ hvNext, float* __restrict__ statsNext,
    const float* __restrict__ oW, const float* __restrict__ ob,
    float* __restrict__ out) {
  __shared__ float Wl[4096];
  __shared__ float fl[3072];
  __shared__ float scl[64], shl[64];
  __shared__ int sS[MAXD], sE[MAXD];
  __shared__ float bsum[64], bsq[64];

  int n = blockIdx.x, t = threadIdx.x;
  for (int i = t; i < 4096; i += 256) Wl[i] = Wg[i];
  if (t < 64) {
    scl[t] = sc[t];
    shl[t] = sh[t];
    bsum[t] = 0.f;
    bsq[t] = 0.f;
  }
  __syncthreads();

  const float4* hv4 = (const float4*)hv;
  const f32x4* heV = (const f32x4*)he;

  // self h1 in fp32 (exact)
  float h1[12];
#pragma unroll
  for (int j = 0; j < 3; j++) {
    int q = t + j * 256;
    int c = q / 12;
    float s = scl[c], b = shl[c];
    float4 v = hv4[(size_t)n * CHW4 + q];
    h1[4 * j + 0] = fmaxf(v.x * s + b, 0.f);
    h1[4 * j + 1] = fmaxf(v.y * s + b, 0.f);
    h1[4 * j + 2] = fmaxf(v.z * s + b, 0.f);
    h1[4 * j + 3] = fmaxf(v.w * s + b, 0.f);
  }

  float S[12], T[12];
#pragma unroll
  for (int i = 0; i < 12; i++) {
    S[i] = 0.f;
    T[i] = 0.f;
  }

  int e0 = off[n], d = off[n + 1] - e0;
  for (int base = 0; base < d; base += MAXD) {
    int cnt = min(MAXD, d - base);
    __syncthreads();
    if (t < cnt) {
      sS[t] = srcs[e0 + base + t];
      if (FIRST) sE[t] = eids[e0 + base + t];
    }
    __syncthreads();

    // ---- software-pipelined edge loop: prefetch k+1 while computing k ----
    u32x2 hgC[3];
    u32x2 hebC[3];
    f32x4 heC[3];
    {
      size_t hb = (size_t)sS[0] * CHW4;
      size_t pb = (size_t)(e0 + base) * CHW4;
#pragma unroll
      for (int j = 0; j < 3; j++) {
        int q = t + j * 256;
        hgC[j] = h1g[hb + q];
        if (FIRST) heC[j] = __builtin_nontemporal_load(&heV[(size_t)sE[0] * CHW4 + q]);
        else hebC[j] = __builtin_nontemporal_load(&heb[pb + q]);
      }
    }
    for (int k = 0; k < cnt; k++) {
      u32x2 hgN[3];
      u32x2 hebN[3];
      f32x4 heN[3];
      if (k + 1 < cnt) {
        size_t hb2 = (size_t)sS[k + 1] * CHW4;
        size_t pb2 = (size_t)(e0 + base + k + 1) * CHW4;
#pragma unroll
        for (int j = 0; j < 3; j++) {
          int q = t + j * 256;
          hgN[j] = h1g[hb2 + q];
          if (FIRST) heN[j] = __builtin_nontemporal_load(&heV[(size_t)sE[k + 1] * CHW4 + q]);
          else hebN[j] = __builtin_nontemporal_load(&heb[pb2 + q]);
        }
      }
      size_t pb = (size_t)(e0 + base + k) * CHW4;
#pragma unroll
      for (int j = 0; j < 3; j++) {
        int q = t + j * 256;
        float hgf[4] = {bf_lo(hgC[j].x), bf_hi(hgC[j].x), bf_lo(hgC[j].y), bf_hi(hgC[j].y)};
        float hef[4];
        if (FIRST) {
          hef[0] = heC[j].x; hef[1] = heC[j].y; hef[2] = heC[j].z; hef[3] = heC[j].w;
          u32x2 o;
          o.x = pack_bf16(heC[j].x, heC[j].y);
          o.y = pack_bf16(heC[j].z, heC[j].w);
          __builtin_nontemporal_store(o, &heb[pb + q]);
        } else {
          hef[0] = bf_lo(hebC[j].x); hef[1] = bf_hi(hebC[j].x);
          hef[2] = bf_lo(hebC[j].y); hef[3] = bf_hi(hebC[j].y);
        }
#pragma unroll
        for (int u = 0; u < 4; u++) {
          float m = fmaxf(hgf[u] + hef[u], 0.f) + 1e-7f;
          float e = __expf(m);  // shift-free softmax: m bounded, no overflow
          int idx = j * 4 + u;
          S[idx] += e;
          T[idx] += e * m;
        }
      }
#pragma unroll
      for (int j = 0; j < 3; j++) {
        hgC[j] = hgN[j];
        if (FIRST) heC[j] = heN[j];
        else hebC[j] = hebN[j];
      }
    }
  }

  bool hasE = d > 0;
  float4* fl4 = (float4*)fl;
#pragma unroll
  for (int j = 0; j < 3; j++) {
    int q = t + j * 256, idx = 4 * j;
    float4 f;
    f.x = h1[idx + 0] + (hasE ? T[idx + 0] / S[idx + 0] : 0.f);
    f.y = h1[idx + 1] + (hasE ? T[idx + 1] / S[idx + 1] : 0.f);
    f.z = h1[idx + 2] + (hasE ? T[idx + 2] / S[idx + 2] : 0.f);
    f.w = h1[idx + 3] + (hasE ? T[idx + 3] / S[idx + 3] : 0.f);
    fl4[q] = f;
  }
  __syncthreads();

  // linear: 192 threads, each owns 4 consecutive out-channels x one h position
  int o0 = (t / 12) * 4, hbp = t % 12;
  float4 acc[4];
  if (t < 192) {
#pragma unroll
    for (int i = 0; i < 4; i++) {
      float bv = bg[o0 + i];
      acc[i] = make_float4(bv, bv, bv, bv);
    }
    const float4* w4 = (const float4*)Wl;
    int widx = o0 >> 2;
    for (int c2 = 0; c2 < 64; c2++) {
      float4 fv = fl4[c2 * 12 + hbp];
      float4 wv = w4[c2 * 16 + widx];
      acc[0].x += wv.x * fv.x; acc[0].y += wv.x * fv.y; acc[0].z += wv.x * fv.z; acc[0].w += wv.x * fv.w;
      acc[1].x += wv.y * fv.x; acc[1].y += wv.y * fv.y; acc[1].z += wv.y * fv.z; acc[1].w += wv.y * fv.w;
      acc[2].x += wv.z * fv.x; acc[2].y += wv.z * fv.y; acc[2].z += wv.z * fv.z; acc[2].w += wv.z * fv.w;
      acc[3].x += wv.w * fv.x; acc[3].y += wv.w * fv.y; acc[3].z += wv.w * fv.z; acc[3].w += wv.w * fv.w;
    }
#pragma unroll
    for (int i = 0; i < 4; i++) {
      float4 r = hv4[(size_t)n * CHW4 + (o0 + i) * 12 + hbp];
      acc[i].x += r.x; acc[i].y += r.y; acc[i].z += r.z; acc[i].w += r.w;
    }
  }

  if constexpr (!LAST) {
    if (t < 192) {
      float4* hn4 = (float4*)hvNext;
#pragma unroll
      for (int i = 0; i < 4; i++) {
        hn4[(size_t)n * CHW4 + (o0 + i) * 12 + hbp] = acc[i];
        float s4 = acc[i].x + acc[i].y + acc[i].z + acc[i].w;
        float q4 = acc[i].x * acc[i].x + acc[i].y * acc[i].y + acc[i].z * acc[i].z + acc[i].w * acc[i].w;
        atomicAdd(&bsum[o0 + i], s4);
        atomicAdd(&bsq[o0 + i], q4);
      }
    }
    __syncthreads();
    int r = n & 7;
    if (t < 64) atomicAdd(&statsNext[r * 128 + t], bsum[t]);
    else if (t < 128) atomicAdd(&statsNext[r * 128 + 64 + (t - 64)], bsq[t - 64]);
  } else {
    __syncthreads();
    if (t < 192) {
#pragma unroll
      for (int i = 0; i < 4; i++) fl4[(o0 + i) * 12 + hbp] = acc[i];
    }
    for (int i = t; i < 768; i += 256) Wl[i] = oW[i];
    __syncthreads();
    for (int i = t; i < 768; i += 256) {
      float4 v = fl4[i];
      Wl[1024 + i] = (v.x + v.y + v.z + v.w) * 0.25f;
    }
    __syncthreads();
    if (t < 144) {
      int o = t / 12, hb = t % 12;
      float bias = ob[o];
      float4 a = make_float4(bias, bias, bias, bias);
      for (int c2 = 0; c2 < 64; c2++) {
        float4 v = fl4[c2 * 12 + hb];
        float wv = Wl[c2 * 12 + o] * Wl[1024 + c2 * 12 + hb];
        a.x += wv * v.x; a.y += wv * v.y; a.z += wv * v.z; a.w += wv * v.w;
      }
      ((float4*)out)[(size_t)n * 144 + t] = a;
    }
  }
}

extern "C" void kernel_launch(void* const* d_in, const int* in_sizes, int n_in,
                              void* d_out, int out_size, void* d_ws, size_t ws_size,
                              hipStream_t stream) {
  const float* node_feats = (const float*)d_in[0];
  const float* edge_feats = (const float*)d_in[1];
  const int* src = (const int*)d_in[2];
  const int* dst = (const int*)d_in[3];
  const float* bn_gamma = (const float*)d_in[4];
  const float* bn_beta = (const float*)d_in[5];
  const float* gen_W = (const float*)d_in[6];
  const float* gen_b = (const float*)d_in[7];
  const float* out_W = (const float*)d_in[8];
  const float* out_b = (const float*)d_in[9];
  float* out = (float*)d_out;

  char* ws = (char*)d_ws;
  float* hvA = (float*)ws;                        // 61,440,000 B
  float* hvB = (float*)(ws + 61440000);           // 61,440,000 B
  u32x2* h1g = (u32x2*)(ws + 122880000);          // 30,720,000 B (bf16 h1)
  u32x2* heb = (u32x2*)(ws + 153600000);          // 307,200,000 B (bf16 he, CSR order)
  float* statsN = (float*)(ws + 460800000);       // 4096 B
  float* sc = (float*)(ws + 460804096);           // 256 B
  float* sh = (float*)(ws + 460804352);           // 256 B
  int* cnt = (int*)(ws + 460804608);              // 20,000 B
  int* off = (int*)(ws + 460824608);              // 20,004 B
  int* cur = (int*)(ws + 460844612);              // 20,000 B
  int* eids = (int*)(ws + 460864612);             // 200,000 B
  int* srcs = (int*)(ws + 461064612);             // 200,000 B

  hipMemsetAsync(cnt, 0, NN * sizeof(int), stream);
  hist_kernel<<<(NE + 255) / 256, 256, 0, stream>>>(dst, cnt);
  scan_kernel<<<1, 256, 0, stream>>>(cnt, off, cur);
  scatter_kernel<<<(NE + 255) / 256, 256, 0, stream>>>(dst, src, cur, eids, srcs);

  hipMemsetAsync(statsN, 0, 1024 * sizeof(float), stream);
  bn_stats_kernel<<<C * SPLIT, 256, 0, stream>>>(node_feats, statsN);

  const float* hvPrev = node_feats;
  float* bufs[2] = {hvA, hvB};
  for (int l = 0; l < 3; l++) {
    finalize2_kernel<<<1, 64, 0, stream>>>(statsN, bn_gamma + l * C, bn_beta + l * C, sc, sh);
    h1_kernel<<<NN * CHW4 / 256, 256, 0, stream>>>(hvPrev, sc, sh, h1g);
    if (l == 0) {
      hipMemsetAsync(statsN, 0, 1024 * sizeof(float), stream);
      aggregate_kernel<true, false><<<NN, 256, 0, stream>>>(
          hvPrev, edge_feats, h1g, heb, srcs, eids, off, gen_W, gen_b,
          sc, sh, bufs[0], statsN, out_W, out_b, out);
      hvPrev = bufs[0];
    } else if (l == 1) {
      hipMemsetAsync(statsN, 0, 1024 * sizeof(float), stream);
      aggregate_kernel<false, false><<<NN, 256, 0, stream>>>(
          hvPrev, edge_feats, h1g, heb, srcs, eids, off, gen_W + C * C, gen_b + C,
          sc, sh, bufs[1], statsN, out_W, out_b, out);
      hvPrev = bufs[1];
    } else {
      aggregate_kernel<false, true><<<NN, 256, 0, stream>>>(
          hvPrev, edge_feats, h1g, heb, srcs, eids, off, gen_W + 2 * C * C, gen_b + 2 * C,
          sc, sh, bufs[0], statsN, out_W, out_b, out);
    }
  }
}

// Round 13
// 562.624 us; speedup vs baseline: 3.0039x; 1.0204x over previous
//
#include <hip/hip_runtime.h>
#include <float.h>

#define NN 5000
#define NE 50000
#define C 64
#define CHW4 768       // float4 units per node row
#define SPLIT 25
#define NPS 200        // 5000/25
#define MAXD 64

typedef float f32x4 __attribute__((ext_vector_type(4)));
typedef unsigned int u32x2 __attribute__((ext_vector_type(2)));

__device__ __forceinline__ unsigned int pack_bf16(float a, float b) {
  unsigned int ua = __float_as_uint(a), ub = __float_as_uint(b);
  ua = (ua + 0x7FFFu + ((ua >> 16) & 1u)) >> 16;
  ub = (ub + 0x7FFFu + ((ub >> 16) & 1u)) & 0xFFFF0000u;
  return ua | ub;
}
__device__ __forceinline__ float bf_lo(unsigned int u) { return __uint_as_float(u << 16); }
__device__ __forceinline__ float bf_hi(unsigned int u) { return __uint_as_float(u & 0xFFFF0000u); }

// per-block BN finalize from replicated stats (call with t < 64)
__device__ __forceinline__ void bn_finalize_block(const float* __restrict__ statsL,
                                                  const float* __restrict__ gamma,
                                                  const float* __restrict__ beta,
                                                  int t, float* scl, float* shl) {
  float s = 0.f, q = 0.f;
#pragma unroll
  for (int r = 0; r < 8; r++) {
    s += statsL[r * 128 + t];
    q += statsL[r * 128 + 64 + t];
  }
  const float inv = 1.f / 240000.f;
  float mu = s * inv;
  float var = q * inv - mu * mu;
  float scale = gamma[t] * rsqrtf(var + 1e-5f);
  scl[t] = scale;
  shl[t] = beta[t] - mu * scale;
}

// ---------------- CSR build ----------------
__global__ void hist_kernel(const int* __restrict__ dst, int* __restrict__ cnt) {
  int e = blockIdx.x * 256 + threadIdx.x;
  if (e < NE) atomicAdd(&cnt[dst[e]], 1);
}

// prefix-sum over node degree + degree-descending node order (LPT schedule)
__global__ void scan_kernel(const int* __restrict__ cnt, int* __restrict__ off,
                            int* __restrict__ cur, int* __restrict__ order) {
  __shared__ int tsum[256];
  __shared__ int dh[64], dof[64];
  int t = threadIdx.x;
  constexpr int PER = 20;
  int base = t * PER;
  int vals[PER];
  int local = 0;
#pragma unroll
  for (int i = 0; i < PER; i++) {
    int idx = base + i;
    int v = (idx < NN) ? cnt[idx] : 0;
    vals[i] = local;
    local += v;
  }
  tsum[t] = local;
  __syncthreads();
  for (int o = 1; o < 256; o <<= 1) {
    int v = (t >= o) ? tsum[t - o] : 0;
    __syncthreads();
    tsum[t] += v;
    __syncthreads();
  }
  int excl = (t == 0) ? 0 : tsum[t - 1];
#pragma unroll
  for (int i = 0; i < PER; i++) {
    int idx = base + i;
    if (idx < NN) {
      int o2 = excl + vals[i];
      off[idx] = o2;
      cur[idx] = o2;
    }
  }
  if (t == 255) off[NN] = excl + local;

  // ---- degree bucket sort (descending): bucket 0 = highest degree ----
  if (t < 64) dh[t] = 0;
  __syncthreads();
  for (int idx = t; idx < NN; idx += 256) {
    int deg = cnt[idx];
    int b = deg > 63 ? 0 : 63 - deg;
    atomicAdd(&dh[b], 1);
  }
  __syncthreads();
  if (t == 0) {
    int s = 0;
    for (int i = 0; i < 64; i++) {
      dof[i] = s;
      s += dh[i];
    }
  }
  __syncthreads();
  if (t < 64) dh[t] = dof[t];
  __syncthreads();
  for (int idx = t; idx < NN; idx += 256) {
    int deg = cnt[idx];
    int b = deg > 63 ? 0 : 63 - deg;
    int p = atomicAdd(&dh[b], 1);
    order[p] = idx;
  }
}

__global__ void scatter_kernel(const int* __restrict__ dst, const int* __restrict__ src,
                               int* __restrict__ cur, int* __restrict__ eids, int* __restrict__ srcs) {
  int e = blockIdx.x * 256 + threadIdx.x;
  if (e < NE) {
    int p = atomicAdd(&cur[dst[e]], 1);
    eids[p] = e;
    srcs[p] = src[e];
  }
}

// ---------------- BatchNorm stats (layer 0 only) ----------------
__global__ void bn_stats_kernel(const float* __restrict__ hv, float* __restrict__ statsN) {
  int c = blockIdx.x / SPLIT, s = blockIdx.x % SPLIT;
  int n0 = s * NPS;
  const float4* hv4 = (const float4*)hv;
  float sum = 0.f, ss = 0.f;
  for (int i = threadIdx.x; i < NPS * 12; i += 256) {
    int n = n0 + i / 12, p = i % 12;
    float4 v = hv4[(size_t)n * CHW4 + c * 12 + p];
    sum += v.x + v.y + v.z + v.w;
    ss += v.x * v.x + v.y * v.y + v.z * v.z + v.w * v.w;
  }
  __shared__ float rs[256], rq[256];
  rs[threadIdx.x] = sum;
  rq[threadIdx.x] = ss;
  __syncthreads();
  for (int o = 128; o > 0; o >>= 1) {
    if (threadIdx.x < o) {
      rs[threadIdx.x] += rs[threadIdx.x + o];
      rq[threadIdx.x] += rq[threadIdx.x + o];
    }
    __syncthreads();
  }
  if (threadIdx.x == 0) {
    int r = blockIdx.x & 7;
    atomicAdd(&statsN[r * 128 + c], rs[0]);
    atomicAdd(&statsN[r * 128 + 64 + c], rq[0]);
  }
}

// ---------------- h1 = BN+ReLU(hv) in bf16 (coalesced pass, inline finalize) ----------------
__global__ __launch_bounds__(256) void h1_kernel(const float* __restrict__ hv,
                                                 const float* __restrict__ statsL,
                                                 const float* __restrict__ gamma,
                                                 const float* __restrict__ beta,
                                                 u32x2* __restrict__ h1g) {
  __shared__ float scl[64], shl[64];
  int t = threadIdx.x;
  if (t < 64) bn_finalize_block(statsL, gamma, beta, t, scl, shl);
  __syncthreads();
  int idx = blockIdx.x * 256 + t;  // float4 index, < NN*768
  int q = idx % CHW4;
  int c = q / 12;
  float s = scl[c], b = shl[c];
  float4 v = ((const float4*)hv)[idx];
  float x0 = fmaxf(v.x * s + b, 0.f);
  float x1 = fmaxf(v.y * s + b, 0.f);
  float x2 = fmaxf(v.z * s + b, 0.f);
  float x3 = fmaxf(v.w * s + b, 0.f);
  u32x2 o;
  o.x = pack_bf16(x0, x1);
  o.y = pack_bf16(x2, x3);
  h1g[idx] = o;
}

// ---------------- Fused GENConv layer ----------------
// Block b processes node order[b] (degree-descending LPT schedule).
// Inline BN finalize; LDS edge staging; bf16 h1g gathers; nt-streamed he/heb.
template <bool FIRST, bool LAST>
__global__ __launch_bounds__(256) void aggregate_kernel(
    const float* __restrict__ hv, const float* __restrict__ he,
    const u32x2* __restrict__ h1g, u32x2* __restrict__ heb,
    const int* __restrict__ srcs, const int* __restrict__ eids, const int* __restrict__ off,
    const int* __restrict__ order,
    const float* __restrict__ Wg, const float* __restrict__ bg,
    const float* __restrict__ gamma, const float* __restrict__ beta,
    const float* __restrict__ statsL,
    float* __restrict__ hvNext, float* __restrict__ statsNext,
    const float* __restrict__ oW, const float* __restrict__ ob,
    float* __restrict__ out) {
  __shared__ float Wl[4096];
  __shared__ float fl[3072];
  __shared__ float scl[64], shl[64];
  __shared__ int sS[MAXD], sE[MAXD];
  __shared__ float bsum[64], bsq[64];

  int n = order[blockIdx.x], t = threadIdx.x;
  for (int i = t; i < 4096; i += 256) Wl[i] = Wg[i];
  if (t < 64) {
    bn_finalize_block(statsL, gamma, beta, t, scl, shl);
    bsum[t] = 0.f;
    bsq[t] = 0.f;
  }
  __syncthreads();

  const float4* hv4 = (const float4*)hv;
  const f32x4* heV = (const f32x4*)he;

  // self h1 in fp32 (exact)
  float h1[12];
#pragma unroll
  for (int j = 0; j < 3; j++) {
    int q = t + j * 256;
    int c = q / 12;
    float s = scl[c], b = shl[c];
    float4 v = hv4[(size_t)n * CHW4 + q];
    h1[4 * j + 0] = fmaxf(v.x * s + b, 0.f);
    h1[4 * j + 1] = fmaxf(v.y * s + b, 0.f);
    h1[4 * j + 2] = fmaxf(v.z * s + b, 0.f);
    h1[4 * j + 3] = fmaxf(v.w * s + b, 0.f);
  }

  float S[12], T[12];
#pragma unroll
  for (int i = 0; i < 12; i++) {
    S[i] = 0.f;
    T[i] = 0.f;
  }

  int e0 = off[n], d = off[n + 1] - e0;
  for (int base = 0; base < d; base += MAXD) {
    int cnt = min(MAXD, d - base);
    __syncthreads();
    if (t < cnt) {
      sS[t] = srcs[e0 + base + t];
      if (FIRST) sE[t] = eids[e0 + base + t];
    }
    __syncthreads();
#pragma unroll 2
    for (int k = 0; k < cnt; k++) {
      size_t hb = (size_t)sS[k] * CHW4;
      size_t pbq = (size_t)(e0 + base + k) * CHW4;  // CSR-slot base for heb
#pragma unroll
      for (int j = 0; j < 3; j++) {
        int q = t + j * 256;
        u32x2 hg = h1g[hb + q];  // bf16 gather (cacheable)
        float hgf[4] = {bf_lo(hg.x), bf_hi(hg.x), bf_lo(hg.y), bf_hi(hg.y)};
        float hef[4];
        if (FIRST) {
          f32x4 b = __builtin_nontemporal_load(&heV[(size_t)sE[k] * CHW4 + q]);
          hef[0] = b.x; hef[1] = b.y; hef[2] = b.z; hef[3] = b.w;
          u32x2 o;
          o.x = pack_bf16(b.x, b.y);
          o.y = pack_bf16(b.z, b.w);
          __builtin_nontemporal_store(o, &heb[pbq + q]);
        } else {
          u32x2 bb = __builtin_nontemporal_load(&heb[pbq + q]);
          hef[0] = bf_lo(bb.x); hef[1] = bf_hi(bb.x); hef[2] = bf_lo(bb.y); hef[3] = bf_hi(bb.y);
        }
#pragma unroll
        for (int u = 0; u < 4; u++) {
          float m = fmaxf(hgf[u] + hef[u], 0.f) + 1e-7f;
          float e = __expf(m);  // shift-free softmax: m bounded, no overflow
          int idx = j * 4 + u;
          S[idx] += e;
          T[idx] += e * m;
        }
      }
    }
  }

  bool hasE = d > 0;
  float4* fl4 = (float4*)fl;
#pragma unroll
  for (int j = 0; j < 3; j++) {
    int q = t + j * 256, idx = 4 * j;
    float4 f;
    f.x = h1[idx + 0] + (hasE ? T[idx + 0] / S[idx + 0] : 0.f);
    f.y = h1[idx + 1] + (hasE ? T[idx + 1] / S[idx + 1] : 0.f);
    f.z = h1[idx + 2] + (hasE ? T[idx + 2] / S[idx + 2] : 0.f);
    f.w = h1[idx + 3] + (hasE ? T[idx + 3] / S[idx + 3] : 0.f);
    fl4[q] = f;
  }
  __syncthreads();

  // linear: 192 threads, each owns 4 consecutive out-channels x one h position
  int o0 = (t / 12) * 4, hbp = t % 12;
  float4 acc[4];
  if (t < 192) {
#pragma unroll
    for (int i = 0; i < 4; i++) {
      float bv = bg[o0 + i];
      acc[i] = make_float4(bv, bv, bv, bv);
    }
    const float4* w4 = (const float4*)Wl;
    int widx = o0 >> 2;
    for (int c2 = 0; c2 < 64; c2++) {
      float4 fv = fl4[c2 * 12 + hbp];
      float4 wv = w4[c2 * 16 + widx];
      acc[0].x += wv.x * fv.x; acc[0].y += wv.x * fv.y; acc[0].z += wv.x * fv.z; acc[0].w += wv.x * fv.w;
      acc[1].x += wv.y * fv.x; acc[1].y += wv.y * fv.y; acc[1].z += wv.y * fv.z; acc[1].w += wv.y * fv.w;
      acc[2].x += wv.z * fv.x; acc[2].y += wv.z * fv.y; acc[2].z += wv.z * fv.z; acc[2].w += wv.z * fv.w;
      acc[3].x += wv.w * fv.x; acc[3].y += wv.w * fv.y; acc[3].z += wv.w * fv.z; acc[3].w += wv.w * fv.w;
    }
#pragma unroll
    for (int i = 0; i < 4; i++) {
      float4 r = hv4[(size_t)n * CHW4 + (o0 + i) * 12 + hbp];
      acc[i].x += r.x; acc[i].y += r.y; acc[i].z += r.z; acc[i].w += r.w;
    }
  }

  if constexpr (!LAST) {
    if (t < 192) {
      float4* hn4 = (float4*)hvNext;
#pragma unroll
      for (int i = 0; i < 4; i++) {
        hn4[(size_t)n * CHW4 + (o0 + i) * 12 + hbp] = acc[i];
        float s4 = acc[i].x + acc[i].y + acc[i].z + acc[i].w;
        float q4 = acc[i].x * acc[i].x + acc[i].y * acc[i].y + acc[i].z * acc[i].z + acc[i].w * acc[i].w;
        atomicAdd(&bsum[o0 + i], s4);
        atomicAdd(&bsq[o0 + i], q4);
      }
    }
    __syncthreads();
    int r = n & 7;
    if (t < 64) atomicAdd(&statsNext[r * 128 + t], bsum[t]);
    else if (t < 128) atomicAdd(&statsNext[r * 128 + 64 + (t - 64)], bsq[t - 64]);
  } else {
    __syncthreads();
    if (t < 192) {
#pragma unroll
      for (int i = 0; i < 4; i++) fl4[(o0 + i) * 12 + hbp] = acc[i];
    }
    for (int i = t; i < 768; i += 256) Wl[i] = oW[i];
    __syncthreads();
    for (int i = t; i < 768; i += 256) {
      float4 v = fl4[i];
      Wl[1024 + i] = (v.x + v.y + v.z + v.w) * 0.25f;
    }
    __syncthreads();
    if (t < 144) {
      int o = t / 12, hb = t % 12;
      float bias = ob[o];
      float4 a = make_float4(bias, bias, bias, bias);
      for (int c2 = 0; c2 < 64; c2++) {
        float4 v = fl4[c2 * 12 + hb];
        float wv = Wl[c2 * 12 + o] * Wl[1024 + c2 * 12 + hb];
        a.x += wv * v.x; a.y += wv * v.y; a.z += wv * v.z; a.w += wv * v.w;
      }
      ((float4*)out)[(size_t)n * 144 + t] = a;
    }
  }
}

extern "C" void kernel_launch(void* const* d_in, const int* in_sizes, int n_in,
                              void* d_out, int out_size, void* d_ws, size_t ws_size,
                              hipStream_t stream) {
  const float* node_feats = (const float*)d_in[0];
  const float* edge_feats = (const float*)d_in[1];
  const int* src = (const int*)d_in[2];
  const int* dst = (const int*)d_in[3];
  const float* bn_gamma = (const float*)d_in[4];
  const float* bn_beta = (const float*)d_in[5];
  const float* gen_W = (const float*)d_in[6];
  const float* gen_b = (const float*)d_in[7];
  const float* out_W = (const float*)d_in[8];
  const float* out_b = (const float*)d_in[9];
  float* out = (float*)d_out;

  char* ws = (char*)d_ws;
  float* hvA = (float*)ws;                        // 61,440,000 B
  float* hvB = (float*)(ws + 61440000);           // 61,440,000 B
  u32x2* h1g = (u32x2*)(ws + 122880000);          // 30,720,000 B (bf16 h1)
  u32x2* heb = (u32x2*)(ws + 153600000);          // 307,200,000 B (bf16 he, CSR order)
  float* statsN = (float*)(ws + 460800000);       // 12,288 B (3 layers x 8 replicas x 128)
  int* cnt = (int*)(ws + 460812288);              // 20,000 B (contiguous after statsN)
  int* off = (int*)(ws + 460832288);              // 20,004 B
  int* cur = (int*)(ws + 460852292);              // 20,000 B
  int* eids = (int*)(ws + 460872292);             // 200,000 B
  int* srcs = (int*)(ws + 461072292);             // 200,000 B
  int* order = (int*)(ws + 461272292);            // 20,000 B

  // one memset covers all 3 per-layer stats buffers + cnt
  hipMemsetAsync(statsN, 0, 12288 + 20000, stream);
  hist_kernel<<<(NE + 255) / 256, 256, 0, stream>>>(dst, cnt);
  scan_kernel<<<1, 256, 0, stream>>>(cnt, off, cur, order);
  scatter_kernel<<<(NE + 255) / 256, 256, 0, stream>>>(dst, src, cur, eids, srcs);
  bn_stats_kernel<<<C * SPLIT, 256, 0, stream>>>(node_feats, statsN);

  // layer 0
  h1_kernel<<<NN * CHW4 / 256, 256, 0, stream>>>(node_feats, statsN, bn_gamma, bn_beta, h1g);
  aggregate_kernel<true, false><<<NN, 256, 0, stream>>>(
      node_feats, edge_feats, h1g, heb, srcs, eids, off, order,
      gen_W, gen_b, bn_gamma, bn_beta, statsN,
      hvA, statsN + 1024, out_W, out_b, out);

  // layer 1
  h1_kernel<<<NN * CHW4 / 256, 256, 0, stream>>>(hvA, statsN + 1024, bn_gamma + C, bn_beta + C, h1g);
  aggregate_kernel<false, false><<<NN, 256, 0, stream>>>(
      hvA, edge_feats, h1g, heb, srcs, eids, off, order,
      gen_W + C * C, gen_b + C, bn_gamma + C, bn_beta + C, statsN + 1024,
      hvB, statsN + 2048, out_W, out_b, out);

  // layer 2 (fused output)
  h1_kernel<<<NN * CHW4 / 256, 256, 0, stream>>>(hvB, statsN + 2048, bn_gamma + 2 * C, bn_beta + 2 * C, h1g);
  aggregate_kernel<false, true><<<NN, 256, 0, stream>>>(
      hvB, edge_feats, h1g, heb, srcs, eids, off, order,
      gen_W + 2 * C * C, gen_b + 2 * C, bn_gamma + 2 * C, bn_beta + 2 * C, statsN + 2048,
      hvA, statsN, out_W, out_b, out);
}